// Round 9
// baseline (235.591 us; speedup 1.0000x reference)
//
#include <hip/hip_runtime.h>
#include <math.h>

#define N_PIX 4096   // H*W
#define C_CH  256
#define NH    4
#define DH    64

typedef __attribute__((ext_vector_type(8))) short bf16x8;
typedef __attribute__((ext_vector_type(4))) float f32x4;

static __device__ __forceinline__ unsigned short f2bf(float f) {
  union { float f; unsigned u; } v; v.f = f;
  unsigned r = v.u + 0x7fffu + ((v.u >> 16) & 1u);  // RNE
  return (unsigned short)(r >> 16);
}
static __device__ __forceinline__ unsigned pk2(float a, float b) {
  return (unsigned)f2bf(a) | ((unsigned)f2bf(b) << 16);
}
// trunc-pack two fp32 -> bf16 pair in ONE v_perm_b32
static __device__ __forceinline__ unsigned pk2t(float a, float b) {
  return __builtin_amdgcn_perm(__float_as_uint(b), __float_as_uint(a),
                               0x07060302u);
}
#if __has_builtin(__builtin_amdgcn_exp2f)
#define EXP2(x) __builtin_amdgcn_exp2f(x)
#else
#define EXP2(x) exp2f(x)
#endif
// XOR-swizzled LDS offset (bf16 elems): rows of 64 elems, 8 granules of 8.
static __device__ __forceinline__ int swz(int row, int g) {
  return (row << 6) + ((((row >> 2) ^ row ^ g) & 7) << 3);
}
// inverse: which source granule lands at linear position p (for direct-to-LDS)
static __device__ __forceinline__ int src_g(int p) {
  int row = p >> 3;
  return (p & 7) ^ ((row ^ (row >> 2)) & 7);
}

#if __has_builtin(__builtin_amdgcn_global_load_lds)
#define HAS_GLL 1
typedef const unsigned int __attribute__((address_space(1)))* as1cu;
typedef unsigned int __attribute__((address_space(3)))* as3u;
// DMA 16 B/lane global->LDS. lds base wave-uniform; lane i lands at +i*16 B.
static __device__ __forceinline__ void gll16(const void* g, void* l) {
  __builtin_amdgcn_global_load_lds((as1cu)g, (as3u)l, 16, 0, 0);
}
#endif

// ---------------------------------------------------------------------------
// GroupNorm stage A (partial sums) + weight fp32->bf16 convert (fused).
// ---------------------------------------------------------------------------
__global__ __launch_bounds__(256) void gn_part_kernel(
    const float* __restrict__ x, const float* __restrict__ wqkv,
    const float* __restrict__ wproj, float* __restrict__ part,
    unsigned short* __restrict__ wB) {
  const int g = blockIdx.x, b = blockIdx.y, z = blockIdx.z;
  const int t = threadIdx.x;
  {
    const int bid = blockIdx.z * 32 + blockIdx.y * 8 + blockIdx.x;
    const int i = bid * 256 + t;
    const float* src = (i < 49152) ? (wqkv + (size_t)i * 4)
                                   : (wproj + (size_t)(i - 49152) * 4);
    float4 v = *(const float4*)src;
    uint2 u;
    u.x = pk2(v.x, v.y);
    u.y = pk2(v.z, v.w);
    *(uint2*)(wB + (size_t)i * 4) = u;
  }
  const float* base = x + (size_t)(b * C_CH + g * 32 + z * 4) * N_PIX;
  float sum = 0.f, sq = 0.f;
  for (int i = t * 4; i < 4 * N_PIX; i += 256 * 4) {
    float4 v = *(const float4*)(base + i);
    sum += v.x + v.y + v.z + v.w;
    sq  += v.x * v.x + v.y * v.y + v.z * v.z + v.w * v.w;
  }
  for (int off = 32; off >= 1; off >>= 1) {
    sum += __shfl_down(sum, off, 64);
    sq  += __shfl_down(sq,  off, 64);
  }
  __shared__ float ps[4], pq[4];
  if ((t & 63) == 0) { ps[t >> 6] = sum; pq[t >> 6] = sq; }
  __syncthreads();
  if (t == 0) {
    int idx = ((b * 8 + g) * 8 + z) * 2;
    part[idx + 0] = ps[0] + ps[1] + ps[2] + ps[3];
    part[idx + 1] = pq[0] + pq[1] + pq[2] + pq[3];
  }
}

// ---------------------------------------------------------------------------
// GN finish + apply + transpose: hT[b][n][c] bf16.
// ---------------------------------------------------------------------------
__global__ __launch_bounds__(256) void gn_apply_kernel(
    const float* __restrict__ x, const float* __restrict__ part,
    const float* __restrict__ gn_w, const float* __restrict__ gn_b,
    unsigned short* __restrict__ hT) {
  const int n0 = blockIdx.x * 64;
  const int c0 = blockIdx.y * 64;
  const int b  = blockIdx.z;
  const int t  = threadIdx.x;
  __shared__ unsigned short Ht[64 * 64];
  __shared__ float ls[64], lsh[64];
  if (t < 64) {
    int c = c0 + t;
    int g = c >> 5;
    float S = 0.f, Q = 0.f;
#pragma unroll
    for (int z = 0; z < 8; ++z) {
      int idx = ((b * 8 + g) * 8 + z) * 2;
      S += part[idx + 0];
      Q += part[idx + 1];
    }
    const float inv_cnt = 1.f / (32.f * N_PIX);
    float mu  = S * inv_cnt;
    float var = Q * inv_cnt - mu * mu;
    float rstd = rsqrtf(var + 1e-5f);
    float s = rstd * gn_w[c];
    ls[t]  = s;
    lsh[t] = gn_b[c] - mu * s;
  }
  __syncthreads();
  const int cl = t >> 4;
  const int nl = (t & 15) * 4;
#pragma unroll
  for (int r = 0; r < 4; ++r) {
    int ce = cl + r * 16;
    float sv = ls[ce], sh = lsh[ce];
    float4 v =
        *(const float4*)(x + ((size_t)(b * C_CH + c0 + ce)) * N_PIX + n0 + nl);
#pragma unroll
    for (int i = 0; i < 4; ++i) {
      float f = ((const float*)&v)[i] * sv + sh;
      Ht[swz(nl + i, ce >> 3) + (ce & 7)] = f2bf(f);
    }
  }
  __syncthreads();
  {
    const int row = t >> 2, sg = (t & 3) * 2;
    uint4 o0 = *(const uint4*)&Ht[swz(row, sg + 0)];
    uint4 o1 = *(const uint4*)&Ht[swz(row, sg + 1)];
    size_t go = ((size_t)(b * N_PIX + n0 + row)) * C_CH + c0 + sg * 8;
    *(uint4*)(hT + go) = o0;
    *(uint4*)(hT + go + 8) = o1;
  }
}

// ---------------------------------------------------------------------------
// QKV GEMM, bf16 MFMA, direct-to-LDS staging (global_load_lds width 16).
// grid (12, 32, 4): type=x>>2 (0=Q,1=K,2=V), head=x&3.
// ---------------------------------------------------------------------------
__global__ __launch_bounds__(256) void qkv_gemm_kernel(
    const unsigned short* __restrict__ hT, const unsigned short* __restrict__ wB,
    const float* __restrict__ bqkv, unsigned short* __restrict__ qT,
    unsigned short* __restrict__ kT, unsigned short* __restrict__ vO) {
  const int mb = blockIdx.x, type = mb >> 2, head = mb & 3;
  const int n0 = blockIdx.y * 128;
  const int b  = blockIdx.z;
  const int t  = threadIdx.x;
  const int wave = t >> 6, lane = t & 63, quad = lane >> 4, lc = lane & 15;

  __shared__ unsigned short Ws[64 * 64];
  __shared__ unsigned short Hs[128 * 64];

  f32x4 acc[4][2];
#pragma unroll
  for (int i = 0; i < 4; ++i)
#pragma unroll
    for (int j = 0; j < 2; ++j) acc[i][j] = (f32x4){0.f, 0.f, 0.f, 0.f};

#ifdef HAS_GLL
  // Ws: 8 chunks (wave: 2), Hs: 16 chunks (wave: 4). src granule permuted.
  const unsigned short* wsrc[2];
  unsigned short* wdst[2];
#pragma unroll
  for (int i = 0; i < 2; ++i) {
    int p = (wave * 2 + i) * 64 + lane;
    wsrc[i] = wB + (size_t)(mb * 64 + (p >> 3)) * C_CH + src_g(p) * 8;
    wdst[i] = &Ws[(wave * 2 + i) * 512];
  }
  const unsigned short* hsrc[4];
  unsigned short* hdst[4];
#pragma unroll
  for (int i = 0; i < 4; ++i) {
    int p = (wave * 4 + i) * 64 + lane;
    hsrc[i] = hT + ((size_t)(b * N_PIX + n0 + (p >> 3))) * C_CH + src_g(p) * 8;
    hdst[i] = &Hs[(wave * 4 + i) * 512];
  }
#else
  const int wrow = t >> 2, wgb = (t & 3) * 2;
  const int hrow = t >> 1, hgb = (t & 1) * 4;
  const unsigned short* wp = wB + (size_t)(mb * 64 + wrow) * C_CH;
  const unsigned short* ap =
      hT + ((size_t)(b * N_PIX + n0 + hrow)) * C_CH + hgb * 8;
#endif

#pragma unroll
  for (int kc = 0; kc < 4; ++kc) {
    const int k0 = kc * 64;
    __syncthreads();
#ifdef HAS_GLL
#pragma unroll
    for (int i = 0; i < 2; ++i) gll16(wsrc[i] + k0, wdst[i]);
#pragma unroll
    for (int i = 0; i < 4; ++i) gll16(hsrc[i] + k0, hdst[i]);
#else
    {
      const unsigned short* s0 = wp + k0 + wgb * 8;
      uint4 u0 = *(const uint4*)(s0);
      uint4 u1 = *(const uint4*)(s0 + 8);
      *(uint4*)&Ws[swz(wrow, wgb + 0)] = u0;
      *(uint4*)&Ws[swz(wrow, wgb + 1)] = u1;
      const unsigned short* s1 = ap + k0;
#pragma unroll
      for (int j = 0; j < 4; ++j) {
        uint4 u = *(const uint4*)(s1 + j * 8);
        *(uint4*)&Hs[swz(hrow, hgb + j)] = u;
      }
    }
#endif
    __syncthreads();
#pragma unroll
    for (int kh = 0; kh < 2; ++kh) {
      bf16x8 wf[4], hf[2];
#pragma unroll
      for (int mt = 0; mt < 4; ++mt)
        wf[mt] = *(const bf16x8*)&Ws[swz(mt * 16 + lc, kh * 4 + quad)];
#pragma unroll
      for (int nt = 0; nt < 2; ++nt)
        hf[nt] = *(const bf16x8*)&Hs[swz(wave * 32 + nt * 16 + lc, kh * 4 + quad)];
      if (type < 2) {
#pragma unroll
        for (int mt = 0; mt < 4; ++mt)
#pragma unroll
          for (int nt = 0; nt < 2; ++nt)
            acc[mt][nt] = __builtin_amdgcn_mfma_f32_16x16x32_bf16(
                wf[mt], hf[nt], acc[mt][nt], 0, 0, 0);
      } else {
#pragma unroll
        for (int mt = 0; mt < 4; ++mt)
#pragma unroll
          for (int nt = 0; nt < 2; ++nt)
            acc[mt][nt] = __builtin_amdgcn_mfma_f32_16x16x32_bf16(
                hf[nt], wf[mt], acc[mt][nt], 0, 0, 0);
      }
    }
  }

  if (type < 2) {
    unsigned short* dst = (type == 0) ? qT : kT;
    const float qs = (type == 0) ? 0.125f * 1.44269504f : 1.0f;
#pragma unroll
    for (int mt = 0; mt < 4; ++mt)
#pragma unroll
      for (int nt = 0; nt < 2; ++nt) {
        int n = n0 + wave * 32 + nt * 16 + lc;
        int d0 = mt * 16 + quad * 4;
        float b0 = bqkv[mb * 64 + d0 + 0], b1 = bqkv[mb * 64 + d0 + 1];
        float b2 = bqkv[mb * 64 + d0 + 2], b3 = bqkv[mb * 64 + d0 + 3];
        uint2 w;
        w.x = pk2((acc[mt][nt][0] + b0) * qs, (acc[mt][nt][1] + b1) * qs);
        w.y = pk2((acc[mt][nt][2] + b2) * qs, (acc[mt][nt][3] + b3) * qs);
        *(uint2*)(dst + ((size_t)((b * NH + head) * N_PIX + n)) * 64 + d0) = w;
      }
  } else {
#pragma unroll
    for (int mt = 0; mt < 4; ++mt)
#pragma unroll
      for (int nt = 0; nt < 2; ++nt) {
        int d = mt * 16 + lc;
        float bias = bqkv[mb * 64 + d];
        int pix = n0 + wave * 32 + nt * 16 + quad * 4;
        uint2 w;
        w.x = pk2(acc[mt][nt][0] + bias, acc[mt][nt][1] + bias);
        w.y = pk2(acc[mt][nt][2] + bias, acc[mt][nt][3] + bias);
        *(uint2*)(vO + ((size_t)((b * NH + head) * 64 + d)) * N_PIX + pix) = w;
      }
  }
}

// ---------------------------------------------------------------------------
// Flash attention, bf16 MFMA, static softmax, Q=128, direct-to-LDS K/V
// staging (global_load_lds width 16: no VGPR roundtrip, no ds_writes).
// Block = (128-q tile, head, batch), 4 waves; wave owns 32 queries.
// ---------------------------------------------------------------------------
__global__ __launch_bounds__(256) void attn_kernel(
    const unsigned short* __restrict__ qT, const unsigned short* __restrict__ kT,
    const unsigned short* __restrict__ vO, unsigned short* __restrict__ aT) {
  const int t  = threadIdx.x;
  const int i0 = blockIdx.x * 128;
  const int h  = blockIdx.y;
  const int b  = blockIdx.z;
  const size_t bh = (size_t)(b * NH + h);
  const unsigned short* qp = qT + bh * N_PIX * 64;
  const unsigned short* kp = kT + bh * N_PIX * 64;
  const unsigned short* vp = vO + bh * 64 * N_PIX;

  __shared__ unsigned short Qt[128 * 64];  // reused as Ps after Q frag loads
  __shared__ unsigned short Kt[64 * 64];
  __shared__ unsigned short Vs[64 * 64];
  unsigned short* const Ps = Qt;

  const int wave = t >> 6, lane = t & 63, quad = lane >> 4, lc = lane & 15;
  const int qb0 = wave * 32, qb1 = wave * 32 + 16;
  const int qrow = t >> 1, qg = (t & 1) * 4;

  // ---- stage Q, load frags (Qt dead afterward)
  {
    const unsigned short* sp = qp + (size_t)(i0 + qrow) * 64 + qg * 8;
#pragma unroll
    for (int i = 0; i < 4; ++i) {
      uint4 u = *(const uint4*)(sp + i * 8);
      *(uint4*)&Qt[swz(qrow, qg + i)] = u;
    }
  }
  __syncthreads();
  bf16x8 aq[2][2];
  aq[0][0] = *(const bf16x8*)&Qt[swz(qb0 + lc, quad)];
  aq[0][1] = *(const bf16x8*)&Qt[swz(qb0 + lc, quad + 4)];
  aq[1][0] = *(const bf16x8*)&Qt[swz(qb1 + lc, quad)];
  aq[1][1] = *(const bf16x8*)&Qt[swz(qb1 + lc, quad + 4)];

  int kof0[4], kof1[4], vof0[4], vof1[4], pw[2][4];
#pragma unroll
  for (int jt = 0; jt < 4; ++jt) {
    kof0[jt] = swz(jt * 16 + lc, quad);
    kof1[jt] = swz(jt * 16 + lc, quad + 4);
    pw[0][jt] = swz(qb0 + lc, jt * 2 + (quad >> 1)) + (quad & 1) * 4;
    pw[1][jt] = swz(qb1 + lc, jt * 2 + (quad >> 1)) + (quad & 1) * 4;
  }
#pragma unroll
  for (int mt = 0; mt < 4; ++mt) {
    vof0[mt] = swz(mt * 16 + lc, quad);
    vof1[mt] = swz(mt * 16 + lc, quad + 4);
  }
  const int pb00 = swz(qb0 + lc, quad), pb01 = swz(qb0 + lc, quad + 4);
  const int pb10 = swz(qb1 + lc, quad), pb11 = swz(qb1 + lc, quad + 4);
  const bf16x8 ones = {16256, 16256, 16256, 16256, 16256, 16256, 16256, 16256};

#ifdef HAS_GLL
  // K/V staging: 8 chunks each (wave: 2+2). source granule permuted.
  const unsigned short* ksrc[2];
  const unsigned short* vsrc[2];
  unsigned short* kdst[2];
  unsigned short* vdst[2];
#pragma unroll
  for (int i = 0; i < 2; ++i) {
    int p = (wave * 2 + i) * 64 + lane;
    int row = p >> 3, g = src_g(p);
    ksrc[i] = kp + (size_t)row * 64 + g * 8;      // +4096 elems per iter
    vsrc[i] = vp + (size_t)row * N_PIX + g * 8;   // +64 elems per iter
    kdst[i] = &Kt[(wave * 2 + i) * 512];
    vdst[i] = &Vs[(wave * 2 + i) * 512];
  }
#else
  const int srow = t >> 2, sg = (t & 3) * 2;
#endif

  f32x4 la0 = (f32x4){0.f, 0.f, 0.f, 0.f};
  f32x4 la1 = (f32x4){0.f, 0.f, 0.f, 0.f};
  f32x4 od[2][4];
#pragma unroll
  for (int qh = 0; qh < 2; ++qh)
#pragma unroll
    for (int mt = 0; mt < 4; ++mt) od[qh][mt] = (f32x4){0.f, 0.f, 0.f, 0.f};

  for (int it = 0; it < 64; ++it) {
    __syncthreads();  // prev iter's Kt/Vs frag reads done
#ifdef HAS_GLL
    {
      const size_t kadv = (size_t)it * 4096;
      const size_t vadv = (size_t)it * 64;
      gll16(ksrc[0] + kadv, kdst[0]);
      gll16(ksrc[1] + kadv, kdst[1]);
      gll16(vsrc[0] + vadv, vdst[0]);
      gll16(vsrc[1] + vadv, vdst[1]);
    }
#else
    {
      const int j0 = it * 64;
      const unsigned short* sk = kp + (size_t)(j0 + srow) * 64 + sg * 8;
      uint4 k0 = *(const uint4*)(sk);
      uint4 k1 = *(const uint4*)(sk + 8);
      *(uint4*)&Kt[swz(srow, sg + 0)] = k0;
      *(uint4*)&Kt[swz(srow, sg + 1)] = k1;
      const unsigned short* sv = vp + (size_t)srow * N_PIX + j0 + sg * 8;
      uint4 v0 = *(const uint4*)(sv);
      uint4 v1 = *(const uint4*)(sv + 8);
      *(uint4*)&Vs[swz(srow, sg + 0)] = v0;
      *(uint4*)&Vs[swz(srow, sg + 1)] = v1;
    }
#endif
    __syncthreads();  // staging complete (vmcnt drained by barrier)

    // ---- S^T = K*Q^T; p = exp2(s); P write (wave-private rows)
#pragma unroll
    for (int jt = 0; jt < 4; ++jt) {
      bf16x8 bk0 = *(const bf16x8*)&Kt[kof0[jt]];
      bf16x8 bk1 = *(const bf16x8*)&Kt[kof1[jt]];
      f32x4 a0 = (f32x4){0.f, 0.f, 0.f, 0.f};
      a0 = __builtin_amdgcn_mfma_f32_16x16x32_bf16(bk0, aq[0][0], a0, 0, 0, 0);
      a0 = __builtin_amdgcn_mfma_f32_16x16x32_bf16(bk1, aq[0][1], a0, 0, 0, 0);
      f32x4 a1 = (f32x4){0.f, 0.f, 0.f, 0.f};
      a1 = __builtin_amdgcn_mfma_f32_16x16x32_bf16(bk0, aq[1][0], a1, 0, 0, 0);
      a1 = __builtin_amdgcn_mfma_f32_16x16x32_bf16(bk1, aq[1][1], a1, 0, 0, 0);
      uint2 u0, u1;
      u0.x = pk2t(EXP2(a0[0]), EXP2(a0[1]));
      u0.y = pk2t(EXP2(a0[2]), EXP2(a0[3]));
      u1.x = pk2t(EXP2(a1[0]), EXP2(a1[1]));
      u1.y = pk2t(EXP2(a1[2]), EXP2(a1[3]));
      *(uint2*)&Ps[pw[0][jt]] = u0;
      *(uint2*)&Ps[pw[1][jt]] = u1;
    }

    // ---- P frags, l, PV
    bf16x8 bp00 = *(const bf16x8*)&Ps[pb00];
    bf16x8 bp01 = *(const bf16x8*)&Ps[pb01];
    bf16x8 bp10 = *(const bf16x8*)&Ps[pb10];
    bf16x8 bp11 = *(const bf16x8*)&Ps[pb11];
    la0 = __builtin_amdgcn_mfma_f32_16x16x32_bf16(ones, bp00, la0, 0, 0, 0);
    la0 = __builtin_amdgcn_mfma_f32_16x16x32_bf16(ones, bp01, la0, 0, 0, 0);
    la1 = __builtin_amdgcn_mfma_f32_16x16x32_bf16(ones, bp10, la1, 0, 0, 0);
    la1 = __builtin_amdgcn_mfma_f32_16x16x32_bf16(ones, bp11, la1, 0, 0, 0);
#pragma unroll
    for (int mt = 0; mt < 4; ++mt) {
      bf16x8 av0 = *(const bf16x8*)&Vs[vof0[mt]];
      bf16x8 av1 = *(const bf16x8*)&Vs[vof1[mt]];
      od[0][mt] =
          __builtin_amdgcn_mfma_f32_16x16x32_bf16(av0, bp00, od[0][mt], 0, 0, 0);
      od[0][mt] =
          __builtin_amdgcn_mfma_f32_16x16x32_bf16(av1, bp01, od[0][mt], 0, 0, 0);
      od[1][mt] =
          __builtin_amdgcn_mfma_f32_16x16x32_bf16(av0, bp10, od[1][mt], 0, 0, 0);
      od[1][mt] =
          __builtin_amdgcn_mfma_f32_16x16x32_bf16(av1, bp11, od[1][mt], 0, 0, 0);
    }
  }

  // ---- epilogue: normalize, O^T -> Ps[q][d] (own rows), coalesced stores
  float inv0 = 1.f / la0[0];
  float inv1 = 1.f / la1[0];
#pragma unroll
  for (int mt = 0; mt < 4; ++mt) {
    uint2 u0, u1;
    u0.x = pk2(od[0][mt][0] * inv0, od[0][mt][1] * inv0);
    u0.y = pk2(od[0][mt][2] * inv0, od[0][mt][3] * inv0);
    u1.x = pk2(od[1][mt][0] * inv1, od[1][mt][1] * inv1);
    u1.y = pk2(od[1][mt][2] * inv1, od[1][mt][3] * inv1);
    *(uint2*)&Ps[swz(qb0 + lc, mt * 2 + (quad >> 1)) + (quad & 1) * 4] = u0;
    *(uint2*)&Ps[swz(qb1 + lc, mt * 2 + (quad >> 1)) + (quad & 1) * 4] = u1;
  }
  __syncthreads();
  {
    size_t go = ((size_t)(b * N_PIX + i0 + qrow)) * C_CH + h * 64 + qg * 8;
#pragma unroll
    for (int i = 0; i < 4; ++i) {
      uint4 o = *(const uint4*)&Ps[swz(qrow, qg + i)];
      *(uint4*)(aT + go + i * 8) = o;
    }
  }
}

// ---------------------------------------------------------------------------
// Proj GEMM, bf16 MFMA, direct-to-LDS staging + fp32 bias/residual.
// ---------------------------------------------------------------------------
__global__ __launch_bounds__(256) void proj_gemm_kernel(
    const unsigned short* __restrict__ aT, const unsigned short* __restrict__ wPB,
    const float* __restrict__ bproj, const float* __restrict__ x,
    float* __restrict__ out) {
  const int m0 = blockIdx.x * 64;
  const int n0 = blockIdx.y * 128;
  const int b  = blockIdx.z;
  const int t  = threadIdx.x;
  const int wave = t >> 6, lane = t & 63, quad = lane >> 4, lc = lane & 15;

  __shared__ unsigned short Ws[64 * 64];
  __shared__ unsigned short Hs[128 * 64];

  f32x4 acc[4][2];
#pragma unroll
  for (int i = 0; i < 4; ++i)
#pragma unroll
    for (int j = 0; j < 2; ++j) acc[i][j] = (f32x4){0.f, 0.f, 0.f, 0.f};

#ifdef HAS_GLL
  const unsigned short* wsrc[2];
  unsigned short* wdst[2];
#pragma unroll
  for (int i = 0; i < 2; ++i) {
    int p = (wave * 2 + i) * 64 + lane;
    wsrc[i] = wPB + (size_t)(m0 + (p >> 3)) * C_CH + src_g(p) * 8;
    wdst[i] = &Ws[(wave * 2 + i) * 512];
  }
  const unsigned short* hsrc[4];
  unsigned short* hdst[4];
#pragma unroll
  for (int i = 0; i < 4; ++i) {
    int p = (wave * 4 + i) * 64 + lane;
    hsrc[i] = aT + ((size_t)(b * N_PIX + n0 + (p >> 3))) * C_CH + src_g(p) * 8;
    hdst[i] = &Hs[(wave * 4 + i) * 512];
  }
#else
  const int wrow = t >> 2, wgb = (t & 3) * 2;
  const int hrow = t >> 1, hgb = (t & 1) * 4;
  const unsigned short* wp = wPB + (size_t)(m0 + wrow) * C_CH;
  const unsigned short* ap =
      aT + ((size_t)(b * N_PIX + n0 + hrow)) * C_CH + hgb * 8;
#endif

#pragma unroll
  for (int kc = 0; kc < 4; ++kc) {
    const int k0 = kc * 64;
    __syncthreads();
#ifdef HAS_GLL
#pragma unroll
    for (int i = 0; i < 2; ++i) gll16(wsrc[i] + k0, wdst[i]);
#pragma unroll
    for (int i = 0; i < 4; ++i) gll16(hsrc[i] + k0, hdst[i]);
#else
    {
      const unsigned short* s0 = wp + k0 + wgb * 8;
      uint4 u0 = *(const uint4*)(s0);
      uint4 u1 = *(const uint4*)(s0 + 8);
      *(uint4*)&Ws[swz(wrow, wgb + 0)] = u0;
      *(uint4*)&Ws[swz(wrow, wgb + 1)] = u1;
      const unsigned short* s1 = ap + k0;
#pragma unroll
      for (int j = 0; j < 4; ++j) {
        uint4 u = *(const uint4*)(s1 + j * 8);
        *(uint4*)&Hs[swz(hrow, hgb + j)] = u;
      }
    }
#endif
    __syncthreads();
#pragma unroll
    for (int kh = 0; kh < 2; ++kh) {
      bf16x8 wf[4], hf[2];
#pragma unroll
      for (int mt = 0; mt < 4; ++mt)
        wf[mt] = *(const bf16x8*)&Ws[swz(mt * 16 + lc, kh * 4 + quad)];
#pragma unroll
      for (int nt = 0; nt < 2; ++nt)
        hf[nt] = *(const bf16x8*)&Hs[swz(wave * 32 + nt * 16 + lc, kh * 4 + quad)];
#pragma unroll
      for (int mt = 0; mt < 4; ++mt)
#pragma unroll
        for (int nt = 0; nt < 2; ++nt)
          acc[mt][nt] = __builtin_amdgcn_mfma_f32_16x16x32_bf16(
              wf[mt], hf[nt], acc[mt][nt], 0, 0, 0);
    }
  }
#pragma unroll
  for (int mt = 0; mt < 4; ++mt) {
#pragma unroll
    for (int nt = 0; nt < 2; ++nt) {
      int n = n0 + wave * 32 + nt * 16 + lc;
#pragma unroll
      for (int r = 0; r < 4; ++r) {
        int c = m0 + mt * 16 + quad * 4 + r;
        size_t gi = ((size_t)(b * C_CH + c)) * N_PIX + n;
        out[gi] = acc[mt][nt][r] + bproj[c] + x[gi];
      }
    }
  }
}

// ---------------------------------------------------------------------------
extern "C" void kernel_launch(void* const* d_in, const int* in_sizes, int n_in,
                              void* d_out, int out_size, void* d_ws,
                              size_t ws_size, hipStream_t stream) {
  const float* x      = (const float*)d_in[0];
  const float* gn_w   = (const float*)d_in[1];
  const float* gn_b   = (const float*)d_in[2];
  const float* w_qkv  = (const float*)d_in[3];
  const float* b_qkv  = (const float*)d_in[4];
  const float* w_proj = (const float*)d_in[5];
  const float* b_proj = (const float*)d_in[6];
  float* out = (float*)d_out;

  float* ws   = (float*)d_ws;
  float* part = ws + 2048;
  unsigned short* qT = (unsigned short*)(ws + 4096);
  unsigned short* kT = qT + (size_t)4194304;
  unsigned short* vO = kT + (size_t)4194304;
  unsigned short* aT = vO + (size_t)4194304;
  unsigned short* hT = aT + (size_t)4194304;
  unsigned short* wB = hT + (size_t)4194304;
  unsigned short* wPB = wB + (size_t)49152 * 4;

  gn_part_kernel<<<dim3(8, 4, 8), dim3(256), 0, stream>>>(x, w_qkv, w_proj,
                                                          part, wB);
  gn_apply_kernel<<<dim3(64, 4, 4), dim3(256), 0, stream>>>(x, part, gn_w,
                                                            gn_b, hT);
  qkv_gemm_kernel<<<dim3(12, 32, 4), dim3(256), 0, stream>>>(
      hT, wB, b_qkv, qT, kT, vO);
  attn_kernel<<<dim3(32, 4, 4), dim3(256), 0, stream>>>(qT, kT, vO, aT);
  proj_gemm_kernel<<<dim3(4, 32, 4), dim3(256), 0, stream>>>(
      aT, wPB, b_proj, x, out);
}

// Round 10
// 214.929 us; speedup vs baseline: 1.0961x; 1.0961x over previous
//
#include <hip/hip_runtime.h>
#include <math.h>

#define N_PIX 4096   // H*W
#define C_CH  256
#define NH    4
#define DH    64

typedef __attribute__((ext_vector_type(8))) short bf16x8;
typedef __attribute__((ext_vector_type(4))) float f32x4;

static __device__ __forceinline__ unsigned short f2bf(float f) {
  union { float f; unsigned u; } v; v.f = f;
  unsigned r = v.u + 0x7fffu + ((v.u >> 16) & 1u);  // RNE
  return (unsigned short)(r >> 16);
}
static __device__ __forceinline__ unsigned pk2(float a, float b) {
  return (unsigned)f2bf(a) | ((unsigned)f2bf(b) << 16);
}
// trunc-pack two fp32 -> bf16 pair in ONE v_perm_b32
static __device__ __forceinline__ unsigned pk2t(float a, float b) {
  return __builtin_amdgcn_perm(__float_as_uint(b), __float_as_uint(a),
                               0x07060302u);
}
#if __has_builtin(__builtin_amdgcn_exp2f)
#define EXP2(x) __builtin_amdgcn_exp2f(x)
#else
#define EXP2(x) exp2f(x)
#endif
// XOR-swizzled LDS offset (bf16 elems): rows of 64 elems, 8 granules of 8.
static __device__ __forceinline__ int swz(int row, int g) {
  return (row << 6) + ((((row >> 2) ^ row ^ g) & 7) << 3);
}

// ---------------------------------------------------------------------------
// GroupNorm stage A (partial sums) + weight fp32->bf16 convert (fused).
// ---------------------------------------------------------------------------
__global__ __launch_bounds__(256) void gn_part_kernel(
    const float* __restrict__ x, const float* __restrict__ wqkv,
    const float* __restrict__ wproj, float* __restrict__ part,
    unsigned short* __restrict__ wB) {
  const int g = blockIdx.x, b = blockIdx.y, z = blockIdx.z;
  const int t = threadIdx.x;
  {
    const int bid = blockIdx.z * 32 + blockIdx.y * 8 + blockIdx.x;
    const int i = bid * 256 + t;
    const float* src = (i < 49152) ? (wqkv + (size_t)i * 4)
                                   : (wproj + (size_t)(i - 49152) * 4);
    float4 v = *(const float4*)src;
    uint2 u;
    u.x = pk2(v.x, v.y);
    u.y = pk2(v.z, v.w);
    *(uint2*)(wB + (size_t)i * 4) = u;
  }
  const float* base = x + (size_t)(b * C_CH + g * 32 + z * 4) * N_PIX;
  float sum = 0.f, sq = 0.f;
  for (int i = t * 4; i < 4 * N_PIX; i += 256 * 4) {
    float4 v = *(const float4*)(base + i);
    sum += v.x + v.y + v.z + v.w;
    sq  += v.x * v.x + v.y * v.y + v.z * v.z + v.w * v.w;
  }
  for (int off = 32; off >= 1; off >>= 1) {
    sum += __shfl_down(sum, off, 64);
    sq  += __shfl_down(sq,  off, 64);
  }
  __shared__ float ps[4], pq[4];
  if ((t & 63) == 0) { ps[t >> 6] = sum; pq[t >> 6] = sq; }
  __syncthreads();
  if (t == 0) {
    int idx = ((b * 8 + g) * 8 + z) * 2;
    part[idx + 0] = ps[0] + ps[1] + ps[2] + ps[3];
    part[idx + 1] = pq[0] + pq[1] + pq[2] + pq[3];
  }
}

// ---------------------------------------------------------------------------
// GN finish + apply + transpose: hT[b][n][c] bf16.
// ---------------------------------------------------------------------------
__global__ __launch_bounds__(256) void gn_apply_kernel(
    const float* __restrict__ x, const float* __restrict__ part,
    const float* __restrict__ gn_w, const float* __restrict__ gn_b,
    unsigned short* __restrict__ hT) {
  const int n0 = blockIdx.x * 64;
  const int c0 = blockIdx.y * 64;
  const int b  = blockIdx.z;
  const int t  = threadIdx.x;
  __shared__ unsigned short Ht[64 * 64];
  __shared__ float ls[64], lsh[64];
  if (t < 64) {
    int c = c0 + t;
    int g = c >> 5;
    float S = 0.f, Q = 0.f;
#pragma unroll
    for (int z = 0; z < 8; ++z) {
      int idx = ((b * 8 + g) * 8 + z) * 2;
      S += part[idx + 0];
      Q += part[idx + 1];
    }
    const float inv_cnt = 1.f / (32.f * N_PIX);
    float mu  = S * inv_cnt;
    float var = Q * inv_cnt - mu * mu;
    float rstd = rsqrtf(var + 1e-5f);
    float s = rstd * gn_w[c];
    ls[t]  = s;
    lsh[t] = gn_b[c] - mu * s;
  }
  __syncthreads();
  const int cl = t >> 4;
  const int nl = (t & 15) * 4;
#pragma unroll
  for (int r = 0; r < 4; ++r) {
    int ce = cl + r * 16;
    float sv = ls[ce], sh = lsh[ce];
    float4 v =
        *(const float4*)(x + ((size_t)(b * C_CH + c0 + ce)) * N_PIX + n0 + nl);
#pragma unroll
    for (int i = 0; i < 4; ++i) {
      float f = ((const float*)&v)[i] * sv + sh;
      Ht[swz(nl + i, ce >> 3) + (ce & 7)] = f2bf(f);
    }
  }
  __syncthreads();
  {
    const int row = t >> 2, sg = (t & 3) * 2;
    uint4 o0 = *(const uint4*)&Ht[swz(row, sg + 0)];
    uint4 o1 = *(const uint4*)&Ht[swz(row, sg + 1)];
    size_t go = ((size_t)(b * N_PIX + n0 + row)) * C_CH + c0 + sg * 8;
    *(uint4*)(hT + go) = o0;
    *(uint4*)(hT + go + 8) = o1;
  }
}

// ---------------------------------------------------------------------------
// QKV GEMM, bf16 MFMA, single-buffer (r6 version).
// grid (12, 32, 4): type=x>>2 (0=Q,1=K,2=V), head=x&3.
// ---------------------------------------------------------------------------
__global__ __launch_bounds__(256) void qkv_gemm_kernel(
    const unsigned short* __restrict__ hT, const unsigned short* __restrict__ wB,
    const float* __restrict__ bqkv, unsigned short* __restrict__ qT,
    unsigned short* __restrict__ kT, unsigned short* __restrict__ vO) {
  const int mb = blockIdx.x, type = mb >> 2, head = mb & 3;
  const int n0 = blockIdx.y * 128;
  const int b  = blockIdx.z;
  const int t  = threadIdx.x;
  const int wave = t >> 6, lane = t & 63, quad = lane >> 4, lc = lane & 15;

  __shared__ unsigned short Ws[64 * 64];
  __shared__ unsigned short Hs[128 * 64];

  f32x4 acc[4][2];
#pragma unroll
  for (int i = 0; i < 4; ++i)
#pragma unroll
    for (int j = 0; j < 2; ++j) acc[i][j] = (f32x4){0.f, 0.f, 0.f, 0.f};

  const int wrow = t >> 2, wgb = (t & 3) * 2;
  const int hrow = t >> 1, hgb = (t & 1) * 4;
  const unsigned short* wp = wB + (size_t)(mb * 64 + wrow) * C_CH;
  const unsigned short* ap =
      hT + ((size_t)(b * N_PIX + n0 + hrow)) * C_CH + hgb * 8;

  for (int k0 = 0; k0 < C_CH; k0 += 64) {
    __syncthreads();
    {
      const unsigned short* s0 = wp + k0 + wgb * 8;
      uint4 u0 = *(const uint4*)(s0);
      uint4 u1 = *(const uint4*)(s0 + 8);
      *(uint4*)&Ws[swz(wrow, wgb + 0)] = u0;
      *(uint4*)&Ws[swz(wrow, wgb + 1)] = u1;
    }
    {
      const unsigned short* s0 = ap + k0;
#pragma unroll
      for (int j = 0; j < 4; ++j) {
        uint4 u = *(const uint4*)(s0 + j * 8);
        *(uint4*)&Hs[swz(hrow, hgb + j)] = u;
      }
    }
    __syncthreads();
#pragma unroll
    for (int kh = 0; kh < 2; ++kh) {
      bf16x8 wf[4], hf[2];
#pragma unroll
      for (int mt = 0; mt < 4; ++mt)
        wf[mt] = *(const bf16x8*)&Ws[swz(mt * 16 + lc, kh * 4 + quad)];
#pragma unroll
      for (int nt = 0; nt < 2; ++nt)
        hf[nt] = *(const bf16x8*)&Hs[swz(wave * 32 + nt * 16 + lc, kh * 4 + quad)];
      if (type < 2) {
#pragma unroll
        for (int mt = 0; mt < 4; ++mt)
#pragma unroll
          for (int nt = 0; nt < 2; ++nt)
            acc[mt][nt] = __builtin_amdgcn_mfma_f32_16x16x32_bf16(
                wf[mt], hf[nt], acc[mt][nt], 0, 0, 0);
      } else {
#pragma unroll
        for (int mt = 0; mt < 4; ++mt)
#pragma unroll
          for (int nt = 0; nt < 2; ++nt)
            acc[mt][nt] = __builtin_amdgcn_mfma_f32_16x16x32_bf16(
                hf[nt], wf[mt], acc[mt][nt], 0, 0, 0);
      }
    }
  }

  if (type < 2) {
    unsigned short* dst = (type == 0) ? qT : kT;
    const float qs = (type == 0) ? 0.125f * 1.44269504f : 1.0f;
#pragma unroll
    for (int mt = 0; mt < 4; ++mt)
#pragma unroll
      for (int nt = 0; nt < 2; ++nt) {
        int n = n0 + wave * 32 + nt * 16 + lc;
        int d0 = mt * 16 + quad * 4;
        float b0 = bqkv[mb * 64 + d0 + 0], b1 = bqkv[mb * 64 + d0 + 1];
        float b2 = bqkv[mb * 64 + d0 + 2], b3 = bqkv[mb * 64 + d0 + 3];
        uint2 w;
        w.x = pk2((acc[mt][nt][0] + b0) * qs, (acc[mt][nt][1] + b1) * qs);
        w.y = pk2((acc[mt][nt][2] + b2) * qs, (acc[mt][nt][3] + b3) * qs);
        *(uint2*)(dst + ((size_t)((b * NH + head) * N_PIX + n)) * 64 + d0) = w;
      }
  } else {
#pragma unroll
    for (int mt = 0; mt < 4; ++mt)
#pragma unroll
      for (int nt = 0; nt < 2; ++nt) {
        int d = mt * 16 + lc;
        float bias = bqkv[mb * 64 + d];
        int pix = n0 + wave * 32 + nt * 16 + quad * 4;
        uint2 w;
        w.x = pk2(acc[mt][nt][0] + bias, acc[mt][nt][1] + bias);
        w.y = pk2(acc[mt][nt][2] + bias, acc[mt][nt][3] + bias);
        *(uint2*)(vO + ((size_t)((b * NH + head) * 64 + d)) * N_PIX + pix) = w;
      }
  }
}

// ---------------------------------------------------------------------------
// Flash attention, bf16 MFMA, static softmax, Q=128, PHASE-PIPELINED:
// iteration it computes scores+exp for tile it while running PV for tile
// it-1 (data-independent -> exp VALU hides under PV MFMA; P LDS round-trip
// gets a full iteration of slack). K/V double-buffered via register relay.
// l accumulated as per-lane fp32 partials (no ones-MFMA), reduced once.
// LDS: Qt/Ps 16KB + Kt 2x8KB + Vs 2x8KB = 48 KB.
// ---------------------------------------------------------------------------
__global__ __launch_bounds__(256) void attn_kernel(
    const unsigned short* __restrict__ qT, const unsigned short* __restrict__ kT,
    const unsigned short* __restrict__ vO, unsigned short* __restrict__ aT) {
  const int t  = threadIdx.x;
  const int i0 = blockIdx.x * 128;
  const int h  = blockIdx.y;
  const int b  = blockIdx.z;
  const size_t bh = (size_t)(b * NH + h);
  const unsigned short* qp = qT + bh * N_PIX * 64;
  const unsigned short* kp = kT + bh * N_PIX * 64;
  const unsigned short* vp = vO + bh * 64 * N_PIX;

  __shared__ unsigned short Qt[128 * 64];  // reused as Ps after Q frag loads
  __shared__ unsigned short Kt[2 * 64 * 64];
  __shared__ unsigned short Vs[2 * 64 * 64];
  unsigned short* const Ps = Qt;

  const int wave = t >> 6, lane = t & 63, quad = lane >> 4, lc = lane & 15;
  const int qb0 = wave * 32, qb1 = wave * 32 + 16;
  const int srow = t >> 2, sg = (t & 3) * 2;
  const int qrow = t >> 1, qg = (t & 1) * 4;

  // ---- stage Q, load frags (Qt dead afterward; all reads are wave-own rows)
  {
    const unsigned short* sp = qp + (size_t)(i0 + qrow) * 64 + qg * 8;
#pragma unroll
    for (int i = 0; i < 4; ++i) {
      uint4 u = *(const uint4*)(sp + i * 8);
      *(uint4*)&Qt[swz(qrow, qg + i)] = u;
    }
  }
  __syncthreads();
  bf16x8 aq[2][2];
  aq[0][0] = *(const bf16x8*)&Qt[swz(qb0 + lc, quad)];
  aq[0][1] = *(const bf16x8*)&Qt[swz(qb0 + lc, quad + 4)];
  aq[1][0] = *(const bf16x8*)&Qt[swz(qb1 + lc, quad)];
  aq[1][1] = *(const bf16x8*)&Qt[swz(qb1 + lc, quad + 4)];

  int kof0[4], kof1[4], vof0[4], vof1[4], pw[2][4];
#pragma unroll
  for (int jt = 0; jt < 4; ++jt) {
    kof0[jt] = swz(jt * 16 + lc, quad);
    kof1[jt] = swz(jt * 16 + lc, quad + 4);
    pw[0][jt] = swz(qb0 + lc, jt * 2 + (quad >> 1)) + (quad & 1) * 4;
    pw[1][jt] = swz(qb1 + lc, jt * 2 + (quad >> 1)) + (quad & 1) * 4;
  }
#pragma unroll
  for (int mt = 0; mt < 4; ++mt) {
    vof0[mt] = swz(mt * 16 + lc, quad);
    vof1[mt] = swz(mt * 16 + lc, quad + 4);
  }
  const int pb00 = swz(qb0 + lc, quad), pb01 = swz(qb0 + lc, quad + 4);
  const int pb10 = swz(qb1 + lc, quad), pb11 = swz(qb1 + lc, quad + 4);
  const int sw0 = swz(srow, sg + 0), sw1 = swz(srow, sg + 1);
  const unsigned short* kbase = kp + (size_t)srow * 64 + sg * 8;
  const unsigned short* vbase = vp + (size_t)srow * N_PIX + sg * 8;

  float la0 = 0.f, la1 = 0.f;  // per-lane partial l (16 keys per iter each)
  f32x4 od[2][4];
#pragma unroll
  for (int qh = 0; qh < 2; ++qh)
#pragma unroll
    for (int mt = 0; mt < 4; ++mt) od[qh][mt] = (f32x4){0.f, 0.f, 0.f, 0.f};

  // ---- prologue: stage tile 0 -> buf0
  {
    uint4 k0 = *(const uint4*)(kbase);
    uint4 k1 = *(const uint4*)(kbase + 8);
    uint4 v0 = *(const uint4*)(vbase);
    uint4 v1 = *(const uint4*)(vbase + 8);
    *(uint4*)&Kt[sw0] = k0;
    *(uint4*)&Kt[sw1] = k1;
    *(uint4*)&Vs[sw0] = v0;
    *(uint4*)&Vs[sw1] = v1;
  }
  __syncthreads();

  // ---- iteration 0: scores + exp + P write (no PV yet); stage tile 1
  {
    uint4 pk0 = *(const uint4*)(kbase + 4096);
    uint4 pk1 = *(const uint4*)(kbase + 4096 + 8);
    uint4 pv0 = *(const uint4*)(vbase + 64);
    uint4 pv1 = *(const uint4*)(vbase + 64 + 8);
#pragma unroll
    for (int jt = 0; jt < 4; ++jt) {
      bf16x8 bk0 = *(const bf16x8*)&Kt[kof0[jt]];
      bf16x8 bk1 = *(const bf16x8*)&Kt[kof1[jt]];
      f32x4 a0 = (f32x4){0.f, 0.f, 0.f, 0.f};
      a0 = __builtin_amdgcn_mfma_f32_16x16x32_bf16(bk0, aq[0][0], a0, 0, 0, 0);
      a0 = __builtin_amdgcn_mfma_f32_16x16x32_bf16(bk1, aq[0][1], a0, 0, 0, 0);
      f32x4 a1 = (f32x4){0.f, 0.f, 0.f, 0.f};
      a1 = __builtin_amdgcn_mfma_f32_16x16x32_bf16(bk0, aq[1][0], a1, 0, 0, 0);
      a1 = __builtin_amdgcn_mfma_f32_16x16x32_bf16(bk1, aq[1][1], a1, 0, 0, 0);
      float e0 = EXP2(a0[0]), e1 = EXP2(a0[1]), e2 = EXP2(a0[2]),
            e3 = EXP2(a0[3]);
      la0 += (e0 + e1) + (e2 + e3);
      uint2 u0;
      u0.x = pk2t(e0, e1);
      u0.y = pk2t(e2, e3);
      *(uint2*)&Ps[pw[0][jt]] = u0;
      float f0 = EXP2(a1[0]), f1 = EXP2(a1[1]), f2 = EXP2(a1[2]),
            f3 = EXP2(a1[3]);
      la1 += (f0 + f1) + (f2 + f3);
      uint2 u1;
      u1.x = pk2t(f0, f1);
      u1.y = pk2t(f2, f3);
      *(uint2*)&Ps[pw[1][jt]] = u1;
    }
    // stage tile 1 -> buf1 (readers wait at next barrier)
    *(uint4*)&Kt[4096 + sw0] = pk0;
    *(uint4*)&Kt[4096 + sw1] = pk1;
    *(uint4*)&Vs[4096 + sw0] = pv0;
    *(uint4*)&Vs[4096 + sw1] = pv1;
  }

  // ---- steady state: scores+exp(it) overlapped with PV(it-1)
  for (int it = 1; it < 64; ++it) {
    const int cb = (it & 1) << 12;  // buffer of tile it (scores)
    const int ob = 4096 - cb;       // buffer of tile it-1 (PV) = staging tgt
    __syncthreads();                // staging of tile it complete
    // prefetch tile it+1 (wraps on last iter; the store goes to a dead buf)
    const size_t kadv = (size_t)((it + 1) & 63) * 4096;
    const size_t vadv = (size_t)((it + 1) & 63) * 64;
    uint4 pk0 = *(const uint4*)(kbase + kadv);
    uint4 pk1 = *(const uint4*)(kbase + kadv + 8);
    uint4 pv0 = *(const uint4*)(vbase + vadv);
    uint4 pv1 = *(const uint4*)(vbase + vadv + 8);

    // scores(it)
    f32x4 s0[4], s1[4];
#pragma unroll
    for (int jt = 0; jt < 4; ++jt) {
      bf16x8 bk0 = *(const bf16x8*)&Kt[cb + kof0[jt]];
      bf16x8 bk1 = *(const bf16x8*)&Kt[cb + kof1[jt]];
      f32x4 a0 = (f32x4){0.f, 0.f, 0.f, 0.f};
      a0 = __builtin_amdgcn_mfma_f32_16x16x32_bf16(bk0, aq[0][0], a0, 0, 0, 0);
      a0 = __builtin_amdgcn_mfma_f32_16x16x32_bf16(bk1, aq[0][1], a0, 0, 0, 0);
      f32x4 a1 = (f32x4){0.f, 0.f, 0.f, 0.f};
      a1 = __builtin_amdgcn_mfma_f32_16x16x32_bf16(bk0, aq[1][0], a1, 0, 0, 0);
      a1 = __builtin_amdgcn_mfma_f32_16x16x32_bf16(bk1, aq[1][1], a1, 0, 0, 0);
      s0[jt] = a0;
      s1[jt] = a1;
    }

    // P(it-1) frags (written last iteration; wave-own rows)
    bf16x8 bp00 = *(const bf16x8*)&Ps[pb00];
    bf16x8 bp01 = *(const bf16x8*)&Ps[pb01];
    bf16x8 bp10 = *(const bf16x8*)&Ps[pb10];
    bf16x8 bp11 = *(const bf16x8*)&Ps[pb11];

    // interleaved: PV(it-1) MFMAs + exp(it) VALU + P(it) writes
#pragma unroll
    for (int mt = 0; mt < 4; ++mt) {
      bf16x8 av0 = *(const bf16x8*)&Vs[ob + vof0[mt]];
      bf16x8 av1 = *(const bf16x8*)&Vs[ob + vof1[mt]];
      od[0][mt] =
          __builtin_amdgcn_mfma_f32_16x16x32_bf16(av0, bp00, od[0][mt], 0, 0, 0);
      od[0][mt] =
          __builtin_amdgcn_mfma_f32_16x16x32_bf16(av1, bp01, od[0][mt], 0, 0, 0);
      od[1][mt] =
          __builtin_amdgcn_mfma_f32_16x16x32_bf16(av0, bp10, od[1][mt], 0, 0, 0);
      od[1][mt] =
          __builtin_amdgcn_mfma_f32_16x16x32_bf16(av1, bp11, od[1][mt], 0, 0, 0);
      float e0 = EXP2(s0[mt][0]), e1 = EXP2(s0[mt][1]), e2 = EXP2(s0[mt][2]),
            e3 = EXP2(s0[mt][3]);
      la0 += (e0 + e1) + (e2 + e3);
      uint2 u0;
      u0.x = pk2t(e0, e1);
      u0.y = pk2t(e2, e3);
      *(uint2*)&Ps[pw[0][mt]] = u0;
      float f0 = EXP2(s1[mt][0]), f1 = EXP2(s1[mt][1]), f2 = EXP2(s1[mt][2]),
            f3 = EXP2(s1[mt][3]);
      la1 += (f0 + f1) + (f2 + f3);
      uint2 u1;
      u1.x = pk2t(f0, f1);
      u1.y = pk2t(f2, f3);
      *(uint2*)&Ps[pw[1][mt]] = u1;
    }

    __syncthreads();  // V(it-1) frag reads complete across all waves
    // stage tile it+1 -> buffer ob (overwrites tile it-1)
    *(uint4*)&Kt[ob + sw0] = pk0;
    *(uint4*)&Kt[ob + sw1] = pk1;
    *(uint4*)&Vs[ob + sw0] = pv0;
    *(uint4*)&Vs[ob + sw1] = pv1;
  }

  // ---- epilogue: PV(63) (tile 63 lives in buf1; P(63) in Ps)
  {
    bf16x8 bp00 = *(const bf16x8*)&Ps[pb00];
    bf16x8 bp01 = *(const bf16x8*)&Ps[pb01];
    bf16x8 bp10 = *(const bf16x8*)&Ps[pb10];
    bf16x8 bp11 = *(const bf16x8*)&Ps[pb11];
#pragma unroll
    for (int mt = 0; mt < 4; ++mt) {
      bf16x8 av0 = *(const bf16x8*)&Vs[4096 + vof0[mt]];
      bf16x8 av1 = *(const bf16x8*)&Vs[4096 + vof1[mt]];
      od[0][mt] =
          __builtin_amdgcn_mfma_f32_16x16x32_bf16(av0, bp00, od[0][mt], 0, 0, 0);
      od[0][mt] =
          __builtin_amdgcn_mfma_f32_16x16x32_bf16(av1, bp01, od[0][mt], 0, 0, 0);
      od[1][mt] =
          __builtin_amdgcn_mfma_f32_16x16x32_bf16(av0, bp10, od[1][mt], 0, 0, 0);
      od[1][mt] =
          __builtin_amdgcn_mfma_f32_16x16x32_bf16(av1, bp11, od[1][mt], 0, 0, 0);
    }
  }

  // ---- l: cross-quad reduce (lanes lc, lc+16, lc+32, lc+48 share a query)
  la0 += __shfl_xor(la0, 16, 64);
  la0 += __shfl_xor(la0, 32, 64);
  la1 += __shfl_xor(la1, 16, 64);
  la1 += __shfl_xor(la1, 32, 64);
  float inv0 = 1.f / la0;
  float inv1 = 1.f / la1;

  // ---- normalize, O^T -> Ps[q][d] (wave-own rows), coalesced [n][c] stores
#pragma unroll
  for (int mt = 0; mt < 4; ++mt) {
    uint2 u0, u1;
    u0.x = pk2(od[0][mt][0] * inv0, od[0][mt][1] * inv0);
    u0.y = pk2(od[0][mt][2] * inv0, od[0][mt][3] * inv0);
    u1.x = pk2(od[1][mt][0] * inv1, od[1][mt][1] * inv1);
    u1.y = pk2(od[1][mt][2] * inv1, od[1][mt][3] * inv1);
    *(uint2*)&Ps[swz(qb0 + lc, mt * 2 + (quad >> 1)) + (quad & 1) * 4] = u0;
    *(uint2*)&Ps[swz(qb1 + lc, mt * 2 + (quad >> 1)) + (quad & 1) * 4] = u1;
  }
  __syncthreads();
  {
    size_t go = ((size_t)(b * N_PIX + i0 + qrow)) * C_CH + h * 64 + qg * 8;
#pragma unroll
    for (int i = 0; i < 4; ++i) {
      uint4 o = *(const uint4*)&Ps[swz(qrow, qg + i)];
      *(uint4*)(aT + go + i * 8) = o;
    }
  }
}

// ---------------------------------------------------------------------------
// Proj GEMM, bf16 MFMA, single-buffer (r6 version) + fp32 bias/residual.
// ---------------------------------------------------------------------------
__global__ __launch_bounds__(256) void proj_gemm_kernel(
    const unsigned short* __restrict__ aT, const unsigned short* __restrict__ wPB,
    const float* __restrict__ bproj, const float* __restrict__ x,
    float* __restrict__ out) {
  const int m0 = blockIdx.x * 64;
  const int n0 = blockIdx.y * 128;
  const int b  = blockIdx.z;
  const int t  = threadIdx.x;
  const int wave = t >> 6, lane = t & 63, quad = lane >> 4, lc = lane & 15;

  __shared__ unsigned short Ws[64 * 64];
  __shared__ unsigned short Hs[128 * 64];

  f32x4 acc[4][2];
#pragma unroll
  for (int i = 0; i < 4; ++i)
#pragma unroll
    for (int j = 0; j < 2; ++j) acc[i][j] = (f32x4){0.f, 0.f, 0.f, 0.f};

  const int wrow = t >> 2, wgb = (t & 3) * 2;
  const int hrow = t >> 1, hgb = (t & 1) * 4;
  const unsigned short* wp = wPB + (size_t)(m0 + wrow) * C_CH;
  const unsigned short* ap =
      aT + ((size_t)(b * N_PIX + n0 + hrow)) * C_CH + hgb * 8;

  for (int k0 = 0; k0 < C_CH; k0 += 64) {
    __syncthreads();
    {
      const unsigned short* s0 = wp + k0 + wgb * 8;
      uint4 u0 = *(const uint4*)(s0);
      uint4 u1 = *(const uint4*)(s0 + 8);
      *(uint4*)&Ws[swz(wrow, wgb + 0)] = u0;
      *(uint4*)&Ws[swz(wrow, wgb + 1)] = u1;
    }
    {
      const unsigned short* s0 = ap + k0;
#pragma unroll
      for (int j = 0; j < 4; ++j) {
        uint4 u = *(const uint4*)(s0 + j * 8);
        *(uint4*)&Hs[swz(hrow, hgb + j)] = u;
      }
    }
    __syncthreads();
#pragma unroll
    for (int kh = 0; kh < 2; ++kh) {
      bf16x8 wf[4], hf[2];
#pragma unroll
      for (int mt = 0; mt < 4; ++mt)
        wf[mt] = *(const bf16x8*)&Ws[swz(mt * 16 + lc, kh * 4 + quad)];
#pragma unroll
      for (int nt = 0; nt < 2; ++nt)
        hf[nt] = *(const bf16x8*)&Hs[swz(wave * 32 + nt * 16 + lc, kh * 4 + quad)];
#pragma unroll
      for (int mt = 0; mt < 4; ++mt)
#pragma unroll
        for (int nt = 0; nt < 2; ++nt)
          acc[mt][nt] = __builtin_amdgcn_mfma_f32_16x16x32_bf16(
              wf[mt], hf[nt], acc[mt][nt], 0, 0, 0);
    }
  }
#pragma unroll
  for (int mt = 0; mt < 4; ++mt) {
#pragma unroll
    for (int nt = 0; nt < 2; ++nt) {
      int n = n0 + wave * 32 + nt * 16 + lc;
#pragma unroll
      for (int r = 0; r < 4; ++r) {
        int c = m0 + mt * 16 + quad * 4 + r;
        size_t gi = ((size_t)(b * C_CH + c)) * N_PIX + n;
        out[gi] = acc[mt][nt][r] + bproj[c] + x[gi];
      }
    }
  }
}

// ---------------------------------------------------------------------------
extern "C" void kernel_launch(void* const* d_in, const int* in_sizes, int n_in,
                              void* d_out, int out_size, void* d_ws,
                              size_t ws_size, hipStream_t stream) {
  const float* x      = (const float*)d_in[0];
  const float* gn_w   = (const float*)d_in[1];
  const float* gn_b   = (const float*)d_in[2];
  const float* w_qkv  = (const float*)d_in[3];
  const float* b_qkv  = (const float*)d_in[4];
  const float* w_proj = (const float*)d_in[5];
  const float* b_proj = (const float*)d_in[6];
  float* out = (float*)d_out;

  float* ws   = (float*)d_ws;
  float* part = ws + 2048;
  unsigned short* qT = (unsigned short*)(ws + 4096);
  unsigned short* kT = qT + (size_t)4194304;
  unsigned short* vO = kT + (size_t)4194304;
  unsigned short* aT = vO + (size_t)4194304;
  unsigned short* hT = aT + (size_t)4194304;
  unsigned short* wB = hT + (size_t)4194304;
  unsigned short* wPB = wB + (size_t)49152 * 4;

  gn_part_kernel<<<dim3(8, 4, 8), dim3(256), 0, stream>>>(x, w_qkv, w_proj,
                                                          part, wB);
  gn_apply_kernel<<<dim3(64, 4, 4), dim3(256), 0, stream>>>(x, part, gn_w,
                                                            gn_b, hT);
  qkv_gemm_kernel<<<dim3(12, 32, 4), dim3(256), 0, stream>>>(
      hT, wB, b_qkv, qT, kT, vO);
  attn_kernel<<<dim3(32, 4, 4), dim3(256), 0, stream>>>(qT, kT, vO, aT);
  proj_gemm_kernel<<<dim3(4, 32, 4), dim3(256), 0, stream>>>(
      aT, wPB, b_proj, x, out);
}

// Round 11
// 209.855 us; speedup vs baseline: 1.1226x; 1.0242x over previous
//
#include <hip/hip_runtime.h>
#include <math.h>

#define N_PIX 4096   // H*W
#define C_CH  256
#define NH    4
#define DH    64

typedef __attribute__((ext_vector_type(8))) short bf16x8;
typedef __attribute__((ext_vector_type(4))) float f32x4;

static __device__ __forceinline__ unsigned short f2bf(float f) {
  union { float f; unsigned u; } v; v.f = f;
  unsigned r = v.u + 0x7fffu + ((v.u >> 16) & 1u);  // RNE
  return (unsigned short)(r >> 16);
}
static __device__ __forceinline__ unsigned pk2(float a, float b) {
  return (unsigned)f2bf(a) | ((unsigned)f2bf(b) << 16);
}
// trunc-pack two fp32 -> bf16 pair in ONE v_perm_b32
static __device__ __forceinline__ unsigned pk2t(float a, float b) {
  return __builtin_amdgcn_perm(__float_as_uint(b), __float_as_uint(a),
                               0x07060302u);
}
#if __has_builtin(__builtin_amdgcn_exp2f)
#define EXP2(x) __builtin_amdgcn_exp2f(x)
#else
#define EXP2(x) exp2f(x)
#endif
// XOR-swizzled LDS offset (bf16 elems): rows of 64 elems, 8 granules of 8.
static __device__ __forceinline__ int swz(int row, int g) {
  return (row << 6) + ((((row >> 2) ^ row ^ g) & 7) << 3);
}

// ---------------------------------------------------------------------------
// GroupNorm stage A (partial sums) + weight fp32->bf16 convert (fused).
// ---------------------------------------------------------------------------
__global__ __launch_bounds__(256) void gn_part_kernel(
    const float* __restrict__ x, const float* __restrict__ wqkv,
    const float* __restrict__ wproj, float* __restrict__ part,
    unsigned short* __restrict__ wB) {
  const int g = blockIdx.x, b = blockIdx.y, z = blockIdx.z;
  const int t = threadIdx.x;
  {
    const int bid = blockIdx.z * 32 + blockIdx.y * 8 + blockIdx.x;
    const int i = bid * 256 + t;
    const float* src = (i < 49152) ? (wqkv + (size_t)i * 4)
                                   : (wproj + (size_t)(i - 49152) * 4);
    float4 v = *(const float4*)src;
    uint2 u;
    u.x = pk2(v.x, v.y);
    u.y = pk2(v.z, v.w);
    *(uint2*)(wB + (size_t)i * 4) = u;
  }
  const float* base = x + (size_t)(b * C_CH + g * 32 + z * 4) * N_PIX;
  float sum = 0.f, sq = 0.f;
  for (int i = t * 4; i < 4 * N_PIX; i += 256 * 4) {
    float4 v = *(const float4*)(base + i);
    sum += v.x + v.y + v.z + v.w;
    sq  += v.x * v.x + v.y * v.y + v.z * v.z + v.w * v.w;
  }
  for (int off = 32; off >= 1; off >>= 1) {
    sum += __shfl_down(sum, off, 64);
    sq  += __shfl_down(sq,  off, 64);
  }
  __shared__ float ps[4], pq[4];
  if ((t & 63) == 0) { ps[t >> 6] = sum; pq[t >> 6] = sq; }
  __syncthreads();
  if (t == 0) {
    int idx = ((b * 8 + g) * 8 + z) * 2;
    part[idx + 0] = ps[0] + ps[1] + ps[2] + ps[3];
    part[idx + 1] = pq[0] + pq[1] + pq[2] + pq[3];
  }
}

// ---------------------------------------------------------------------------
// GN finish + apply + transpose: hT[b][n][c] bf16.
// ---------------------------------------------------------------------------
__global__ __launch_bounds__(256) void gn_apply_kernel(
    const float* __restrict__ x, const float* __restrict__ part,
    const float* __restrict__ gn_w, const float* __restrict__ gn_b,
    unsigned short* __restrict__ hT) {
  const int n0 = blockIdx.x * 64;
  const int c0 = blockIdx.y * 64;
  const int b  = blockIdx.z;
  const int t  = threadIdx.x;
  __shared__ unsigned short Ht[64 * 64];
  __shared__ float ls[64], lsh[64];
  if (t < 64) {
    int c = c0 + t;
    int g = c >> 5;
    float S = 0.f, Q = 0.f;
#pragma unroll
    for (int z = 0; z < 8; ++z) {
      int idx = ((b * 8 + g) * 8 + z) * 2;
      S += part[idx + 0];
      Q += part[idx + 1];
    }
    const float inv_cnt = 1.f / (32.f * N_PIX);
    float mu  = S * inv_cnt;
    float var = Q * inv_cnt - mu * mu;
    float rstd = rsqrtf(var + 1e-5f);
    float s = rstd * gn_w[c];
    ls[t]  = s;
    lsh[t] = gn_b[c] - mu * s;
  }
  __syncthreads();
  const int cl = t >> 4;
  const int nl = (t & 15) * 4;
#pragma unroll
  for (int r = 0; r < 4; ++r) {
    int ce = cl + r * 16;
    float sv = ls[ce], sh = lsh[ce];
    float4 v =
        *(const float4*)(x + ((size_t)(b * C_CH + c0 + ce)) * N_PIX + n0 + nl);
#pragma unroll
    for (int i = 0; i < 4; ++i) {
      float f = ((const float*)&v)[i] * sv + sh;
      Ht[swz(nl + i, ce >> 3) + (ce & 7)] = f2bf(f);
    }
  }
  __syncthreads();
  {
    const int row = t >> 2, sg = (t & 3) * 2;
    uint4 o0 = *(const uint4*)&Ht[swz(row, sg + 0)];
    uint4 o1 = *(const uint4*)&Ht[swz(row, sg + 1)];
    size_t go = ((size_t)(b * N_PIX + n0 + row)) * C_CH + c0 + sg * 8;
    *(uint4*)(hT + go) = o0;
    *(uint4*)(hT + go + 8) = o1;
  }
}

// ---------------------------------------------------------------------------
// QKV GEMM, bf16 MFMA, Q+K+V MERGED per block: one 128-px Hs staging serves
// all three 64-row W tiles (staging bytes/MFMA 1.5 -> 0.83 KB).
// grid (4 heads, 32 n-tiles, 4 batch).
// Q out pre-scaled by log2(e)/8 (exp2-domain static softmax downstream).
// ---------------------------------------------------------------------------
__global__ __launch_bounds__(256) void qkv_gemm_kernel(
    const unsigned short* __restrict__ hT, const unsigned short* __restrict__ wB,
    const float* __restrict__ bqkv, unsigned short* __restrict__ qT,
    unsigned short* __restrict__ kT, unsigned short* __restrict__ vO) {
  const int head = blockIdx.x;
  const int n0 = blockIdx.y * 128;
  const int b  = blockIdx.z;
  const int t  = threadIdx.x;
  const int wave = t >> 6, lane = t & 63, quad = lane >> 4, lc = lane & 15;

  __shared__ unsigned short Ws[3 * 64 * 64];  // [type][m][k] swizzled, 24 KB
  __shared__ unsigned short Hs[128 * 64];     // [n][k] swizzled, 16 KB

  f32x4 acc[3][4][2];
#pragma unroll
  for (int ty = 0; ty < 3; ++ty)
#pragma unroll
    for (int i = 0; i < 4; ++i)
#pragma unroll
      for (int j = 0; j < 2; ++j) acc[ty][i][j] = (f32x4){0.f, 0.f, 0.f, 0.f};

  const int wrow = t >> 2, wgb = (t & 3) * 2;
  const int hrow = t >> 1, hgb = (t & 1) * 4;
  // W rows: type ty lives at rows ty*256 + head*64 + [0,64)
  const unsigned short* wp =
      wB + (size_t)(head * 64 + wrow) * C_CH + wgb * 8;
  const unsigned short* ap =
      hT + ((size_t)(b * N_PIX + n0 + hrow)) * C_CH + hgb * 8;
  const int wsw0 = swz(wrow, wgb + 0), wsw1 = swz(wrow, wgb + 1);
  int hsw[4];
#pragma unroll
  for (int j = 0; j < 4; ++j) hsw[j] = swz(hrow, hgb + j);

  for (int kc = 0; kc < 4; ++kc) {
    const int k0 = kc * 64;
    __syncthreads();
#pragma unroll
    for (int ty = 0; ty < 3; ++ty) {
      const unsigned short* s0 = wp + (size_t)ty * 256 * C_CH + k0;
      uint4 u0 = *(const uint4*)(s0);
      uint4 u1 = *(const uint4*)(s0 + 8);
      *(uint4*)&Ws[ty * 4096 + wsw0] = u0;
      *(uint4*)&Ws[ty * 4096 + wsw1] = u1;
    }
    {
      const unsigned short* s0 = ap + k0;
#pragma unroll
      for (int j = 0; j < 4; ++j) {
        uint4 u = *(const uint4*)(s0 + j * 8);
        *(uint4*)&Hs[hsw[j]] = u;
      }
    }
    __syncthreads();
#pragma unroll
    for (int kh = 0; kh < 2; ++kh) {
      bf16x8 hf[2];
#pragma unroll
      for (int nt = 0; nt < 2; ++nt)
        hf[nt] = *(const bf16x8*)&Hs[swz(wave * 32 + nt * 16 + lc, kh * 4 + quad)];
#pragma unroll
      for (int ty = 0; ty < 3; ++ty) {
        bf16x8 wf[4];
#pragma unroll
        for (int mt = 0; mt < 4; ++mt)
          wf[mt] =
              *(const bf16x8*)&Ws[ty * 4096 + swz(mt * 16 + lc, kh * 4 + quad)];
        if (ty < 2) {
#pragma unroll
          for (int mt = 0; mt < 4; ++mt)
#pragma unroll
            for (int nt = 0; nt < 2; ++nt)
              acc[ty][mt][nt] = __builtin_amdgcn_mfma_f32_16x16x32_bf16(
                  wf[mt], hf[nt], acc[ty][mt][nt], 0, 0, 0);
        } else {  // V: D[pixel][channel]
#pragma unroll
          for (int mt = 0; mt < 4; ++mt)
#pragma unroll
            for (int nt = 0; nt < 2; ++nt)
              acc[2][mt][nt] = __builtin_amdgcn_mfma_f32_16x16x32_bf16(
                  hf[nt], wf[mt], acc[2][mt][nt], 0, 0, 0);
        }
      }
    }
  }

  // ---- epilogues
#pragma unroll
  for (int ty = 0; ty < 2; ++ty) {
    unsigned short* dst = (ty == 0) ? qT : kT;
    const float qs = (ty == 0) ? 0.125f * 1.44269504f : 1.0f;
    const int bb = ty * 256 + head * 64;
#pragma unroll
    for (int mt = 0; mt < 4; ++mt)
#pragma unroll
      for (int nt = 0; nt < 2; ++nt) {
        int n = n0 + wave * 32 + nt * 16 + lc;
        int d0 = mt * 16 + quad * 4;
        float b0 = bqkv[bb + d0 + 0], b1 = bqkv[bb + d0 + 1];
        float b2 = bqkv[bb + d0 + 2], b3 = bqkv[bb + d0 + 3];
        uint2 w;
        w.x = pk2((acc[ty][mt][nt][0] + b0) * qs, (acc[ty][mt][nt][1] + b1) * qs);
        w.y = pk2((acc[ty][mt][nt][2] + b2) * qs, (acc[ty][mt][nt][3] + b3) * qs);
        *(uint2*)(dst + ((size_t)((b * NH + head) * N_PIX + n)) * 64 + d0) = w;
      }
  }
  {
    const int bb = 512 + head * 64;
#pragma unroll
    for (int mt = 0; mt < 4; ++mt)
#pragma unroll
      for (int nt = 0; nt < 2; ++nt) {
        int d = mt * 16 + lc;
        float bias = bqkv[bb + d];
        int pix = n0 + wave * 32 + nt * 16 + quad * 4;
        uint2 w;
        w.x = pk2(acc[2][mt][nt][0] + bias, acc[2][mt][nt][1] + bias);
        w.y = pk2(acc[2][mt][nt][2] + bias, acc[2][mt][nt][3] + bias);
        *(uint2*)(vO + ((size_t)((b * NH + head) * 64 + d)) * N_PIX + pix) = w;
      }
  }
}

// ---------------------------------------------------------------------------
// Flash attention, bf16 MFMA, static softmax, Q=128, PHASE-PIPELINED
// (r10 WIN version, unchanged): scores+exp(it) overlapped with PV(it-1).
// ---------------------------------------------------------------------------
__global__ __launch_bounds__(256) void attn_kernel(
    const unsigned short* __restrict__ qT, const unsigned short* __restrict__ kT,
    const unsigned short* __restrict__ vO, unsigned short* __restrict__ aT) {
  const int t  = threadIdx.x;
  const int i0 = blockIdx.x * 128;
  const int h  = blockIdx.y;
  const int b  = blockIdx.z;
  const size_t bh = (size_t)(b * NH + h);
  const unsigned short* qp = qT + bh * N_PIX * 64;
  const unsigned short* kp = kT + bh * N_PIX * 64;
  const unsigned short* vp = vO + bh * 64 * N_PIX;

  __shared__ unsigned short Qt[128 * 64];  // reused as Ps after Q frag loads
  __shared__ unsigned short Kt[2 * 64 * 64];
  __shared__ unsigned short Vs[2 * 64 * 64];
  unsigned short* const Ps = Qt;

  const int wave = t >> 6, lane = t & 63, quad = lane >> 4, lc = lane & 15;
  const int qb0 = wave * 32, qb1 = wave * 32 + 16;
  const int srow = t >> 2, sg = (t & 3) * 2;
  const int qrow = t >> 1, qg = (t & 1) * 4;

  {
    const unsigned short* sp = qp + (size_t)(i0 + qrow) * 64 + qg * 8;
#pragma unroll
    for (int i = 0; i < 4; ++i) {
      uint4 u = *(const uint4*)(sp + i * 8);
      *(uint4*)&Qt[swz(qrow, qg + i)] = u;
    }
  }
  __syncthreads();
  bf16x8 aq[2][2];
  aq[0][0] = *(const bf16x8*)&Qt[swz(qb0 + lc, quad)];
  aq[0][1] = *(const bf16x8*)&Qt[swz(qb0 + lc, quad + 4)];
  aq[1][0] = *(const bf16x8*)&Qt[swz(qb1 + lc, quad)];
  aq[1][1] = *(const bf16x8*)&Qt[swz(qb1 + lc, quad + 4)];

  int kof0[4], kof1[4], vof0[4], vof1[4], pw[2][4];
#pragma unroll
  for (int jt = 0; jt < 4; ++jt) {
    kof0[jt] = swz(jt * 16 + lc, quad);
    kof1[jt] = swz(jt * 16 + lc, quad + 4);
    pw[0][jt] = swz(qb0 + lc, jt * 2 + (quad >> 1)) + (quad & 1) * 4;
    pw[1][jt] = swz(qb1 + lc, jt * 2 + (quad >> 1)) + (quad & 1) * 4;
  }
#pragma unroll
  for (int mt = 0; mt < 4; ++mt) {
    vof0[mt] = swz(mt * 16 + lc, quad);
    vof1[mt] = swz(mt * 16 + lc, quad + 4);
  }
  const int pb00 = swz(qb0 + lc, quad), pb01 = swz(qb0 + lc, quad + 4);
  const int pb10 = swz(qb1 + lc, quad), pb11 = swz(qb1 + lc, quad + 4);
  const int sw0 = swz(srow, sg + 0), sw1 = swz(srow, sg + 1);
  const unsigned short* kbase = kp + (size_t)srow * 64 + sg * 8;
  const unsigned short* vbase = vp + (size_t)srow * N_PIX + sg * 8;

  float la0 = 0.f, la1 = 0.f;
  f32x4 od[2][4];
#pragma unroll
  for (int qh = 0; qh < 2; ++qh)
#pragma unroll
    for (int mt = 0; mt < 4; ++mt) od[qh][mt] = (f32x4){0.f, 0.f, 0.f, 0.f};

  {
    uint4 k0 = *(const uint4*)(kbase);
    uint4 k1 = *(const uint4*)(kbase + 8);
    uint4 v0 = *(const uint4*)(vbase);
    uint4 v1 = *(const uint4*)(vbase + 8);
    *(uint4*)&Kt[sw0] = k0;
    *(uint4*)&Kt[sw1] = k1;
    *(uint4*)&Vs[sw0] = v0;
    *(uint4*)&Vs[sw1] = v1;
  }
  __syncthreads();

  {
    uint4 pk0 = *(const uint4*)(kbase + 4096);
    uint4 pk1 = *(const uint4*)(kbase + 4096 + 8);
    uint4 pv0 = *(const uint4*)(vbase + 64);
    uint4 pv1 = *(const uint4*)(vbase + 64 + 8);
#pragma unroll
    for (int jt = 0; jt < 4; ++jt) {
      bf16x8 bk0 = *(const bf16x8*)&Kt[kof0[jt]];
      bf16x8 bk1 = *(const bf16x8*)&Kt[kof1[jt]];
      f32x4 a0 = (f32x4){0.f, 0.f, 0.f, 0.f};
      a0 = __builtin_amdgcn_mfma_f32_16x16x32_bf16(bk0, aq[0][0], a0, 0, 0, 0);
      a0 = __builtin_amdgcn_mfma_f32_16x16x32_bf16(bk1, aq[0][1], a0, 0, 0, 0);
      f32x4 a1 = (f32x4){0.f, 0.f, 0.f, 0.f};
      a1 = __builtin_amdgcn_mfma_f32_16x16x32_bf16(bk0, aq[1][0], a1, 0, 0, 0);
      a1 = __builtin_amdgcn_mfma_f32_16x16x32_bf16(bk1, aq[1][1], a1, 0, 0, 0);
      float e0 = EXP2(a0[0]), e1 = EXP2(a0[1]), e2 = EXP2(a0[2]),
            e3 = EXP2(a0[3]);
      la0 += (e0 + e1) + (e2 + e3);
      uint2 u0;
      u0.x = pk2t(e0, e1);
      u0.y = pk2t(e2, e3);
      *(uint2*)&Ps[pw[0][jt]] = u0;
      float f0 = EXP2(a1[0]), f1 = EXP2(a1[1]), f2 = EXP2(a1[2]),
            f3 = EXP2(a1[3]);
      la1 += (f0 + f1) + (f2 + f3);
      uint2 u1;
      u1.x = pk2t(f0, f1);
      u1.y = pk2t(f2, f3);
      *(uint2*)&Ps[pw[1][jt]] = u1;
    }
    *(uint4*)&Kt[4096 + sw0] = pk0;
    *(uint4*)&Kt[4096 + sw1] = pk1;
    *(uint4*)&Vs[4096 + sw0] = pv0;
    *(uint4*)&Vs[4096 + sw1] = pv1;
  }

  for (int it = 1; it < 64; ++it) {
    const int cb = (it & 1) << 12;
    const int ob = 4096 - cb;
    __syncthreads();
    const size_t kadv = (size_t)((it + 1) & 63) * 4096;
    const size_t vadv = (size_t)((it + 1) & 63) * 64;
    uint4 pk0 = *(const uint4*)(kbase + kadv);
    uint4 pk1 = *(const uint4*)(kbase + kadv + 8);
    uint4 pv0 = *(const uint4*)(vbase + vadv);
    uint4 pv1 = *(const uint4*)(vbase + vadv + 8);

    f32x4 s0[4], s1[4];
#pragma unroll
    for (int jt = 0; jt < 4; ++jt) {
      bf16x8 bk0 = *(const bf16x8*)&Kt[cb + kof0[jt]];
      bf16x8 bk1 = *(const bf16x8*)&Kt[cb + kof1[jt]];
      f32x4 a0 = (f32x4){0.f, 0.f, 0.f, 0.f};
      a0 = __builtin_amdgcn_mfma_f32_16x16x32_bf16(bk0, aq[0][0], a0, 0, 0, 0);
      a0 = __builtin_amdgcn_mfma_f32_16x16x32_bf16(bk1, aq[0][1], a0, 0, 0, 0);
      f32x4 a1 = (f32x4){0.f, 0.f, 0.f, 0.f};
      a1 = __builtin_amdgcn_mfma_f32_16x16x32_bf16(bk0, aq[1][0], a1, 0, 0, 0);
      a1 = __builtin_amdgcn_mfma_f32_16x16x32_bf16(bk1, aq[1][1], a1, 0, 0, 0);
      s0[jt] = a0;
      s1[jt] = a1;
    }

    bf16x8 bp00 = *(const bf16x8*)&Ps[pb00];
    bf16x8 bp01 = *(const bf16x8*)&Ps[pb01];
    bf16x8 bp10 = *(const bf16x8*)&Ps[pb10];
    bf16x8 bp11 = *(const bf16x8*)&Ps[pb11];

#pragma unroll
    for (int mt = 0; mt < 4; ++mt) {
      bf16x8 av0 = *(const bf16x8*)&Vs[ob + vof0[mt]];
      bf16x8 av1 = *(const bf16x8*)&Vs[ob + vof1[mt]];
      od[0][mt] =
          __builtin_amdgcn_mfma_f32_16x16x32_bf16(av0, bp00, od[0][mt], 0, 0, 0);
      od[0][mt] =
          __builtin_amdgcn_mfma_f32_16x16x32_bf16(av1, bp01, od[0][mt], 0, 0, 0);
      od[1][mt] =
          __builtin_amdgcn_mfma_f32_16x16x32_bf16(av0, bp10, od[1][mt], 0, 0, 0);
      od[1][mt] =
          __builtin_amdgcn_mfma_f32_16x16x32_bf16(av1, bp11, od[1][mt], 0, 0, 0);
      float e0 = EXP2(s0[mt][0]), e1 = EXP2(s0[mt][1]), e2 = EXP2(s0[mt][2]),
            e3 = EXP2(s0[mt][3]);
      la0 += (e0 + e1) + (e2 + e3);
      uint2 u0;
      u0.x = pk2t(e0, e1);
      u0.y = pk2t(e2, e3);
      *(uint2*)&Ps[pw[0][mt]] = u0;
      float f0 = EXP2(s1[mt][0]), f1 = EXP2(s1[mt][1]), f2 = EXP2(s1[mt][2]),
            f3 = EXP2(s1[mt][3]);
      la1 += (f0 + f1) + (f2 + f3);
      uint2 u1;
      u1.x = pk2t(f0, f1);
      u1.y = pk2t(f2, f3);
      *(uint2*)&Ps[pw[1][mt]] = u1;
    }

    __syncthreads();
    *(uint4*)&Kt[ob + sw0] = pk0;
    *(uint4*)&Kt[ob + sw1] = pk1;
    *(uint4*)&Vs[ob + sw0] = pv0;
    *(uint4*)&Vs[ob + sw1] = pv1;
  }

  {
    bf16x8 bp00 = *(const bf16x8*)&Ps[pb00];
    bf16x8 bp01 = *(const bf16x8*)&Ps[pb01];
    bf16x8 bp10 = *(const bf16x8*)&Ps[pb10];
    bf16x8 bp11 = *(const bf16x8*)&Ps[pb11];
#pragma unroll
    for (int mt = 0; mt < 4; ++mt) {
      bf16x8 av0 = *(const bf16x8*)&Vs[4096 + vof0[mt]];
      bf16x8 av1 = *(const bf16x8*)&Vs[4096 + vof1[mt]];
      od[0][mt] =
          __builtin_amdgcn_mfma_f32_16x16x32_bf16(av0, bp00, od[0][mt], 0, 0, 0);
      od[0][mt] =
          __builtin_amdgcn_mfma_f32_16x16x32_bf16(av1, bp01, od[0][mt], 0, 0, 0);
      od[1][mt] =
          __builtin_amdgcn_mfma_f32_16x16x32_bf16(av0, bp10, od[1][mt], 0, 0, 0);
      od[1][mt] =
          __builtin_amdgcn_mfma_f32_16x16x32_bf16(av1, bp11, od[1][mt], 0, 0, 0);
    }
  }

  la0 += __shfl_xor(la0, 16, 64);
  la0 += __shfl_xor(la0, 32, 64);
  la1 += __shfl_xor(la1, 16, 64);
  la1 += __shfl_xor(la1, 32, 64);
  float inv0 = 1.f / la0;
  float inv1 = 1.f / la1;

#pragma unroll
  for (int mt = 0; mt < 4; ++mt) {
    uint2 u0, u1;
    u0.x = pk2(od[0][mt][0] * inv0, od[0][mt][1] * inv0);
    u0.y = pk2(od[0][mt][2] * inv0, od[0][mt][3] * inv0);
    u1.x = pk2(od[1][mt][0] * inv1, od[1][mt][1] * inv1);
    u1.y = pk2(od[1][mt][2] * inv1, od[1][mt][3] * inv1);
    *(uint2*)&Ps[swz(qb0 + lc, mt * 2 + (quad >> 1)) + (quad & 1) * 4] = u0;
    *(uint2*)&Ps[swz(qb1 + lc, mt * 2 + (quad >> 1)) + (quad & 1) * 4] = u1;
  }
  __syncthreads();
  {
    size_t go = ((size_t)(b * N_PIX + i0 + qrow)) * C_CH + h * 64 + qg * 8;
#pragma unroll
    for (int i = 0; i < 4; ++i) {
      uint4 o = *(const uint4*)&Ps[swz(qrow, qg + i)];
      *(uint4*)(aT + go + i * 8) = o;
    }
  }
}

// ---------------------------------------------------------------------------
// Proj GEMM, bf16 MFMA, single-buffer + fp32 bias/residual.
// ---------------------------------------------------------------------------
__global__ __launch_bounds__(256) void proj_gemm_kernel(
    const unsigned short* __restrict__ aT, const unsigned short* __restrict__ wPB,
    const float* __restrict__ bproj, const float* __restrict__ x,
    float* __restrict__ out) {
  const int m0 = blockIdx.x * 64;
  const int n0 = blockIdx.y * 128;
  const int b  = blockIdx.z;
  const int t  = threadIdx.x;
  const int wave = t >> 6, lane = t & 63, quad = lane >> 4, lc = lane & 15;

  __shared__ unsigned short Ws[64 * 64];
  __shared__ unsigned short Hs[128 * 64];

  f32x4 acc[4][2];
#pragma unroll
  for (int i = 0; i < 4; ++i)
#pragma unroll
    for (int j = 0; j < 2; ++j) acc[i][j] = (f32x4){0.f, 0.f, 0.f, 0.f};

  const int wrow = t >> 2, wgb = (t & 3) * 2;
  const int hrow = t >> 1, hgb = (t & 1) * 4;
  const unsigned short* wp = wPB + (size_t)(m0 + wrow) * C_CH;
  const unsigned short* ap =
      aT + ((size_t)(b * N_PIX + n0 + hrow)) * C_CH + hgb * 8;

  for (int k0 = 0; k0 < C_CH; k0 += 64) {
    __syncthreads();
    {
      const unsigned short* s0 = wp + k0 + wgb * 8;
      uint4 u0 = *(const uint4*)(s0);
      uint4 u1 = *(const uint4*)(s0 + 8);
      *(uint4*)&Ws[swz(wrow, wgb + 0)] = u0;
      *(uint4*)&Ws[swz(wrow, wgb + 1)] = u1;
    }
    {
      const unsigned short* s0 = ap + k0;
#pragma unroll
      for (int j = 0; j < 4; ++j) {
        uint4 u = *(const uint4*)(s0 + j * 8);
        *(uint4*)&Hs[swz(hrow, hgb + j)] = u;
      }
    }
    __syncthreads();
#pragma unroll
    for (int kh = 0; kh < 2; ++kh) {
      bf16x8 wf[4], hf[2];
#pragma unroll
      for (int mt = 0; mt < 4; ++mt)
        wf[mt] = *(const bf16x8*)&Ws[swz(mt * 16 + lc, kh * 4 + quad)];
#pragma unroll
      for (int nt = 0; nt < 2; ++nt)
        hf[nt] = *(const bf16x8*)&Hs[swz(wave * 32 + nt * 16 + lc, kh * 4 + quad)];
#pragma unroll
      for (int mt = 0; mt < 4; ++mt)
#pragma unroll
        for (int nt = 0; nt < 2; ++nt)
          acc[mt][nt] = __builtin_amdgcn_mfma_f32_16x16x32_bf16(
              wf[mt], hf[nt], acc[mt][nt], 0, 0, 0);
    }
  }
#pragma unroll
  for (int mt = 0; mt < 4; ++mt) {
#pragma unroll
    for (int nt = 0; nt < 2; ++nt) {
      int n = n0 + wave * 32 + nt * 16 + lc;
#pragma unroll
      for (int r = 0; r < 4; ++r) {
        int c = m0 + mt * 16 + quad * 4 + r;
        size_t gi = ((size_t)(b * C_CH + c)) * N_PIX + n;
        out[gi] = acc[mt][nt][r] + bproj[c] + x[gi];
      }
    }
  }
}

// ---------------------------------------------------------------------------
extern "C" void kernel_launch(void* const* d_in, const int* in_sizes, int n_in,
                              void* d_out, int out_size, void* d_ws,
                              size_t ws_size, hipStream_t stream) {
  const float* x      = (const float*)d_in[0];
  const float* gn_w   = (const float*)d_in[1];
  const float* gn_b   = (const float*)d_in[2];
  const float* w_qkv  = (const float*)d_in[3];
  const float* b_qkv  = (const float*)d_in[4];
  const float* w_proj = (const float*)d_in[5];
  const float* b_proj = (const float*)d_in[6];
  float* out = (float*)d_out;

  float* ws   = (float*)d_ws;
  float* part = ws + 2048;
  unsigned short* qT = (unsigned short*)(ws + 4096);
  unsigned short* kT = qT + (size_t)4194304;
  unsigned short* vO = kT + (size_t)4194304;
  unsigned short* aT = vO + (size_t)4194304;
  unsigned short* hT = aT + (size_t)4194304;
  unsigned short* wB = hT + (size_t)4194304;
  unsigned short* wPB = wB + (size_t)49152 * 4;

  gn_part_kernel<<<dim3(8, 4, 8), dim3(256), 0, stream>>>(x, w_qkv, w_proj,
                                                          part, wB);
  gn_apply_kernel<<<dim3(64, 4, 4), dim3(256), 0, stream>>>(x, part, gn_w,
                                                            gn_b, hT);
  qkv_gemm_kernel<<<dim3(4, 32, 4), dim3(256), 0, stream>>>(
      hT, wB, b_qkv, qT, kT, vO);
  attn_kernel<<<dim3(32, 4, 4), dim3(256), 0, stream>>>(qT, kT, vO, aT);
  proj_gemm_kernel<<<dim3(4, 32, 4), dim3(256), 0, stream>>>(
      aT, wPB, b_proj, x, out);
}